// Round 6
// baseline (377.205 us; speedup 1.0000x reference)
//
#include <hip/hip_runtime.h>

// Problem constants (reference: B=8, N=8192, D=64, NNZ=2097152)
#define NB 8
#define NN 8192
#define ND 64

// Binning geometry: 512 buckets x 128 output rows; 4 sub-buckets each to
// reduce counter contention. Sub-bucket mean occupancy = 2M*0.25/2048 = 256,
// sigma ~16 -> SUBCAP=512 is ~16 sigma; spill path is correctness insurance.
#define NBKT 512
#define ROWS_PER_BKT 128
#define SUB 4
#define NSLOT (NBKT * SUB)    // 2048
#define SUBCAP 512
#define SPILLCAP 16384

// ---------------------------------------------------------------------------
// Mask normalization (bool upload convention unknown: 1-byte vs int32).
// Wave-parallel detection: words of X_mask > 1 => byte-packed bools.
// ---------------------------------------------------------------------------
__global__ void mask_prep_kernel(const void* __restrict__ xm_raw,
                                 const void* __restrict__ tm_raw,
                                 unsigned int* __restrict__ xm_out,
                                 unsigned int* __restrict__ tm_out,
                                 int n) {
    __shared__ int s_is_bytes;
    if (threadIdx.x == 0) s_is_bytes = 0;
    __syncthreads();
    {
        const unsigned int* w = (const unsigned int*)xm_raw;
        if (threadIdx.x < 256 && w[threadIdx.x] > 1u) atomicOr(&s_is_bytes, 1);
    }
    __syncthreads();
    const int idx = blockIdx.x * blockDim.x + threadIdx.x;
    if (idx >= n) return;
    unsigned int xv, tv;
    if (s_is_bytes) {
        xv = ((const unsigned char*)xm_raw)[idx];
        tv = ((const unsigned char*)tm_raw)[idx];
    } else {
        xv = ((const unsigned int*)xm_raw)[idx];
        tv = ((const unsigned int*)tm_raw)[idx];
    }
    xm_out[idx] = xv ? 1u : 0u;
    tm_out[idx] = tv ? 1u : 0u;
}

// ---------------------------------------------------------------------------
// Pass 1: bin surviving edges into sub-buckets. int4-vectorized index reads
// (4 edges/thread/iter). Entry = (xrow | row_in_bucket<<16, val_bits).
// ---------------------------------------------------------------------------
__global__ void bin_kernel(const int* __restrict__ Ab, const int* __restrict__ Ar,
                           const int* __restrict__ Ac, const float* __restrict__ Av,
                           const unsigned int* __restrict__ Xm,
                           const unsigned int* __restrict__ Tm,
                           unsigned int* __restrict__ cnt,
                           int2* __restrict__ buckets,
                           unsigned int* __restrict__ spill_cnt,
                           int2* __restrict__ spill,
                           int nq) {
    const int sub = blockIdx.x & (SUB - 1);
    const int4*   Ab4 = (const int4*)Ab;
    const int4*   Ar4 = (const int4*)Ar;
    const int4*   Ac4 = (const int4*)Ac;
    const float4* Av4 = (const float4*)Av;
    int i = blockIdx.x * blockDim.x + threadIdx.x;
    const int str = gridDim.x * blockDim.x;
    for (; i < nq; i += str) {
        const int4   b4 = Ab4[i];
        const int4   r4 = Ar4[i];
        const int4   c4 = Ac4[i];
        const float4 v4 = Av4[i];
        const int   bs[4] = {b4.x, b4.y, b4.z, b4.w};
        const int   rs[4] = {r4.x, r4.y, r4.z, r4.w};
        const int   cs[4] = {c4.x, c4.y, c4.z, c4.w};
        const float vs[4] = {v4.x, v4.y, v4.z, v4.w};
        #pragma unroll
        for (int j = 0; j < 4; ++j) {
            const int seg  = bs[j] * NN + rs[j];
            const int xrow = bs[j] * NN + cs[j];
            if (Tm[seg] && Xm[xrow]) {
                const int slot = (seg >> 7) * SUB + sub;
                const unsigned int pos = atomicAdd(&cnt[slot], 1u);
                if (pos < SUBCAP) {
                    buckets[(size_t)slot * SUBCAP + pos] =
                        make_int2(xrow | ((seg & (ROWS_PER_BKT - 1)) << 16),
                                  __float_as_int(vs[j]));
                } else {
                    const unsigned int sp = atomicAdd(spill_cnt, 1u);
                    if (sp < SPILLCAP)
                        spill[sp] = make_int2(xrow | (seg << 16), __float_as_int(vs[j]));
                }
            }
        }
    }
}

// ---------------------------------------------------------------------------
// Pass 2: one block per bucket. 128 rows x 64 f32 accumulator in LDS (32 KB).
// 16 waves stream the bucket's entries (lane == d); LDS float atomicAdd
// (acc[row*64+lane]: 2-way bank aliasing = free). One contiguous 32 KB
// float4 write per block -- this also zero-fills masked / empty rows, so no
// global memset of out is needed.
// ---------------------------------------------------------------------------
__global__ __launch_bounds__(1024) void accum_kernel(const unsigned int* __restrict__ cnt,
                                                     const int2* __restrict__ buckets,
                                                     const float* __restrict__ X,
                                                     float* __restrict__ out) {
    __shared__ float acc[ROWS_PER_BKT * ND];   // 32 KB
    const int bkt = blockIdx.x;
    float4* a4 = (float4*)acc;
    for (int i = threadIdx.x; i < ROWS_PER_BKT * ND / 4; i += blockDim.x)
        a4[i] = make_float4(0.f, 0.f, 0.f, 0.f);
    __syncthreads();
    const int wave = threadIdx.x >> 6;
    const int lane = threadIdx.x & 63;
    const int nw   = blockDim.x >> 6;          // 16 waves
    #pragma unroll
    for (int sub = 0; sub < SUB; ++sub) {
        const int slot = bkt * SUB + sub;
        const unsigned int n = min(cnt[slot], (unsigned int)SUBCAP);
        const int2* base = buckets + (size_t)slot * SUBCAP;
        for (unsigned int k = wave; k < n; k += nw) {
            const int2 e   = base[k];                 // uniform across the wave
            const int xrow = e.x & 0xFFFF;
            const int row  = e.x >> 16;               // 0..127
            const float v  = __int_as_float(e.y);
            atomicAdd(&acc[row * ND + lane], v * X[((size_t)xrow << 6) + lane]);
        }
    }
    __syncthreads();
    float4* o4 = (float4*)(out + (size_t)bkt * ROWS_PER_BKT * ND);
    for (int i = threadIdx.x; i < ROWS_PER_BKT * ND / 4; i += blockDim.x)
        o4[i] = a4[i];
}

// ---------------------------------------------------------------------------
// Pass 3: spill entries (expected 0). Global-atomic adds on top of accum's
// output. Entry = (xrow | seg<<16, val_bits).
// ---------------------------------------------------------------------------
__global__ void spill_kernel(const unsigned int* __restrict__ spill_cnt,
                             const int2* __restrict__ spill,
                             const float* __restrict__ X,
                             float* __restrict__ out) {
    const unsigned int n = min(*spill_cnt, (unsigned int)SPILLCAP);
    const int lane = threadIdx.x & 63;
    const int g0   = blockIdx.x * (blockDim.x >> 6) + (threadIdx.x >> 6);
    const int gstr = gridDim.x * (blockDim.x >> 6);
    for (unsigned int k = g0; k < n; k += gstr) {
        const int2 e   = spill[k];
        const int xrow = e.x & 0xFFFF;
        const int seg  = (e.x >> 16) & 0xFFFF;
        atomicAdd(&out[((size_t)seg << 6) + lane],
                  __int_as_float(e.y) * X[((size_t)xrow << 6) + lane]);
    }
}

// ---------------------------------------------------------------------------
// Fallback: round-2 proven atomic scatter (unexpected shape or small ws).
// ---------------------------------------------------------------------------
__global__ void coo_scatter_kernel(const int* __restrict__ Ab,
                                   const int* __restrict__ Ar,
                                   const int* __restrict__ Ac,
                                   const float* __restrict__ Av,
                                   const float* __restrict__ X,
                                   const unsigned int* __restrict__ Xm,
                                   const unsigned int* __restrict__ Tm,
                                   float* __restrict__ out, int nnz) {
    const int groups_per_block = blockDim.x >> 6;
    const int g0 = blockIdx.x * groups_per_block + (threadIdx.x >> 6);
    const int gstr = gridDim.x * groups_per_block;
    const int lane = threadIdx.x & 63;
    for (int e = g0; e < nnz; e += gstr) {
        const int b = Ab[e];
        const int r = Ar[e];
        if (!Tm[b * NN + r]) continue;
        const int c = Ac[e];
        if (!Xm[b * NN + c]) continue;
        const float v = Av[e];
        const float x = X[((size_t)(b * NN + c)) * ND + lane];
        atomicAdd(&out[((size_t)(b * NN + r)) * ND + lane], v * x);
    }
}

extern "C" void kernel_launch(void* const* d_in, const int* in_sizes, int n_in,
                              void* d_out, int out_size, void* d_ws, size_t ws_size,
                              hipStream_t stream) {
    const int*   Ab = (const int*)d_in[0];
    const int*   Ar = (const int*)d_in[1];
    const int*   Ac = (const int*)d_in[2];
    const float* Av = (const float*)d_in[3];
    const float* X  = (const float*)d_in[4];
    const void*  Xm_raw = d_in[5];
    const void*  Tm_raw = d_in[6];
    float* out = (float*)d_out;

    const int nnz   = in_sizes[0];
    const int nmask = in_sizes[5];   // B*N

    // Workspace layout (8B aligned)
    unsigned char* w = (unsigned char*)d_ws;
    unsigned int* xm        = (unsigned int*)w;  w += (size_t)nmask * 4;
    unsigned int* tm        = (unsigned int*)w;  w += (size_t)nmask * 4;
    unsigned int* cnt       = (unsigned int*)w;  w += (size_t)NSLOT * 4;
    unsigned int* spill_cnt = (unsigned int*)w;  w += 16;                    // padded
    int2*         buckets   = (int2*)w;          w += (size_t)NSLOT * SUBCAP * 8;
    int2*         spill     = (int2*)w;          w += (size_t)SPILLCAP * 8;
    const size_t needed = (size_t)(w - (unsigned char*)d_ws);

    mask_prep_kernel<<<(nmask + 255) / 256, 256, 0, stream>>>(Xm_raw, Tm_raw, xm, tm, nmask);

    // Fast path requires the known problem shape (16-bit xrow/seg packing,
    // sub-bucket capacity sized for nnz=2M at ~25% survival).
    if (ws_size < needed || nmask != NBKT * ROWS_PER_BKT || (nnz & 3) || nnz > (1 << 22)) {
        hipMemsetAsync(d_out, 0, (size_t)out_size * sizeof(float), stream);
        coo_scatter_kernel<<<16384, 256, 0, stream>>>(Ab, Ar, Ac, Av, X, xm, tm, out, nnz);
        return;
    }

    // Zero cnt[] and spill_cnt (adjacent) in one memset. No out memset needed:
    // accum_kernel writes every output row.
    hipMemsetAsync(cnt, 0, (size_t)NSLOT * 4 + 16, stream);

    const int nq = nnz >> 2;                 // 524288 int4 groups
    bin_kernel<<<2048, 256, 0, stream>>>(Ab, Ar, Ac, Av, xm, tm,
                                         cnt, buckets, spill_cnt, spill, nq);
    accum_kernel<<<NBKT, 1024, 0, stream>>>(cnt, buckets, X, out);
    spill_kernel<<<16, 256, 0, stream>>>(spill_cnt, spill, X, out);
}

// Round 10
// 174.862 us; speedup vs baseline: 2.1572x; 2.1572x over previous
//
#include <hip/hip_runtime.h>

// Problem constants (reference: B=8, N=8192, D=64, NNZ=2097152)
#define NB 8
#define NN 8192
#define ND 64

// Binning geometry: 512 buckets x 128 output rows; 4 sub-buckets each.
// Sub-bucket mean occupancy = 2M*0.25/2048 = 256, sigma~16 -> SUBCAP=512 is
// ~16 sigma. Counters padded to one per 64B L2 line (CNT_STRIDE u32) to kill
// per-line atomic serialization (round-6 lesson: 16 counters/line = 4K
// serialized atomics/line = 160us).
#define NBKT 512
#define ROWS_PER_BKT 128
#define SUB 4
#define NSLOT (NBKT * SUB)      // 2048
#define SUBCAP 512
#define BKT_CAP (SUB * SUBCAP)  // 2048 entries max per bucket
#define CNT_STRIDE 16           // 64B per counter
#define SPILLCAP 16384

// ---------------------------------------------------------------------------
// Mask normalization (bool upload convention unknown: 1-byte vs int32).
// ---------------------------------------------------------------------------
__global__ void mask_prep_kernel(const void* __restrict__ xm_raw,
                                 const void* __restrict__ tm_raw,
                                 unsigned int* __restrict__ xm_out,
                                 unsigned int* __restrict__ tm_out,
                                 int n) {
    __shared__ int s_is_bytes;
    if (threadIdx.x == 0) s_is_bytes = 0;
    __syncthreads();
    {
        const unsigned int* w = (const unsigned int*)xm_raw;
        if (threadIdx.x < 256 && w[threadIdx.x] > 1u) atomicOr(&s_is_bytes, 1);
    }
    __syncthreads();
    const int idx = blockIdx.x * blockDim.x + threadIdx.x;
    if (idx >= n) return;
    unsigned int xv, tv;
    if (s_is_bytes) {
        xv = ((const unsigned char*)xm_raw)[idx];
        tv = ((const unsigned char*)tm_raw)[idx];
    } else {
        xv = ((const unsigned int*)xm_raw)[idx];
        tv = ((const unsigned int*)tm_raw)[idx];
    }
    xm_out[idx] = xv ? 1u : 0u;
    tm_out[idx] = tv ? 1u : 0u;
}

// ---------------------------------------------------------------------------
// Pass 1: bin surviving edges into sub-buckets. int4-vectorized reads.
// Entry = (xrow | row_in_bucket<<16, val_bits). Padded counters.
// ---------------------------------------------------------------------------
__global__ void bin_kernel(const int* __restrict__ Ab, const int* __restrict__ Ar,
                           const int* __restrict__ Ac, const float* __restrict__ Av,
                           const unsigned int* __restrict__ Xm,
                           const unsigned int* __restrict__ Tm,
                           unsigned int* __restrict__ cnt,
                           int2* __restrict__ buckets,
                           unsigned int* __restrict__ spill_cnt,
                           int2* __restrict__ spill,
                           int nq) {
    const int sub = blockIdx.x & (SUB - 1);
    const int4*   Ab4 = (const int4*)Ab;
    const int4*   Ar4 = (const int4*)Ar;
    const int4*   Ac4 = (const int4*)Ac;
    const float4* Av4 = (const float4*)Av;
    int i = blockIdx.x * blockDim.x + threadIdx.x;
    const int str = gridDim.x * blockDim.x;
    for (; i < nq; i += str) {
        const int4   b4 = Ab4[i];
        const int4   r4 = Ar4[i];
        const int4   c4 = Ac4[i];
        const float4 v4 = Av4[i];
        const int   bs[4] = {b4.x, b4.y, b4.z, b4.w};
        const int   rs[4] = {r4.x, r4.y, r4.z, r4.w};
        const int   cs[4] = {c4.x, c4.y, c4.z, c4.w};
        const float vs[4] = {v4.x, v4.y, v4.z, v4.w};
        #pragma unroll
        for (int j = 0; j < 4; ++j) {
            const int seg  = bs[j] * NN + rs[j];
            const int xrow = bs[j] * NN + cs[j];
            if (Tm[seg] && Xm[xrow]) {
                const int slot = (seg >> 7) * SUB + sub;
                const unsigned int pos = atomicAdd(&cnt[slot * CNT_STRIDE], 1u);
                if (pos < SUBCAP) {
                    buckets[(size_t)slot * SUBCAP + pos] =
                        make_int2(xrow | ((seg & (ROWS_PER_BKT - 1)) << 16),
                                  __float_as_int(vs[j]));
                } else {
                    const unsigned int sp = atomicAdd(spill_cnt, 1u);
                    if (sp < SPILLCAP)
                        spill[sp] = make_int2(xrow | (seg << 16), __float_as_int(vs[j]));
                }
            }
        }
    }
}

// ---------------------------------------------------------------------------
// Pass 2: one block (1024 thr) per bucket.
//   a) stage <=2048 entries from global (coalesced, 2/thread max)
//   b) LDS histogram by row (native u32 LDS atomics)
//   c) wave-0 shfl exclusive scan of 128 row counts
//   d) scatter entries into row-sorted LDS order
//   e) wave w accumulates rows 8w..8w+7 in 8 VGPRs (no atomics at all),
//      writes 8 coalesced 256B rows. Also zero-fills empty/masked rows ->
//      no global memset of out needed.
// ---------------------------------------------------------------------------
__global__ __launch_bounds__(1024) void accum_kernel(const unsigned int* __restrict__ cnt,
                                                     const int2* __restrict__ buckets,
                                                     const float* __restrict__ X,
                                                     float* __restrict__ out) {
    __shared__ int2 sorted[BKT_CAP];                   // 16 KB
    __shared__ unsigned int hist[ROWS_PER_BKT];
    __shared__ unsigned int rowstart[ROWS_PER_BKT + 1];
    __shared__ unsigned int cursor[ROWS_PER_BKT];
    __shared__ unsigned int s_n[SUB];

    const int bkt = blockIdx.x;
    const int t = threadIdx.x;

    if (t < ROWS_PER_BKT) hist[t] = 0;
    if (t < SUB) s_n[t] = min(cnt[(bkt * SUB + t) * CNT_STRIDE], (unsigned int)SUBCAP);
    __syncthreads();

    // a+b) stage + histogram (entry idx space: sub = idx/SUBCAP, off = idx%SUBCAP)
    int2 e0, e1;
    int r0 = -1, r1 = -1;
    {
        int idx = t, sub = idx >> 9, off = idx & (SUBCAP - 1);
        if ((unsigned int)off < s_n[sub]) {
            e0 = buckets[(size_t)(bkt * SUB + sub) * SUBCAP + off];
            r0 = (e0.x >> 16) & (ROWS_PER_BKT - 1);
            atomicAdd(&hist[r0], 1u);
        }
        idx = t + 1024; sub = idx >> 9; off = idx & (SUBCAP - 1);
        if ((unsigned int)off < s_n[sub]) {
            e1 = buckets[(size_t)(bkt * SUB + sub) * SUBCAP + off];
            r1 = (e1.x >> 16) & (ROWS_PER_BKT - 1);
            atomicAdd(&hist[r1], 1u);
        }
    }
    __syncthreads();

    // c) exclusive scan of 128 counts by wave 0 (two 64-wide shfl scans)
    if (t < 64) {
        const unsigned int h0 = hist[t], h1 = hist[64 + t];
        unsigned int a = h0, b = h1;
        for (int off = 1; off < 64; off <<= 1) {
            unsigned int v = __shfl_up(a, off);
            if (t >= off) a += v;
        }
        const unsigned int atot = __shfl(a, 63);
        for (int off = 1; off < 64; off <<= 1) {
            unsigned int v = __shfl_up(b, off);
            if (t >= off) b += v;
        }
        rowstart[t]      = a - h0;
        rowstart[64 + t] = atot + b - h1;
        cursor[t]        = a - h0;
        cursor[64 + t]   = atot + b - h1;
        if (t == 63) rowstart[128] = atot + b;
    }
    __syncthreads();

    // d) scatter into row-sorted order
    if (r0 >= 0) { const unsigned int p = atomicAdd(&cursor[r0], 1u); sorted[p] = e0; }
    if (r1 >= 0) { const unsigned int p = atomicAdd(&cursor[r1], 1u); sorted[p] = e1; }
    __syncthreads();

    // e) register accumulation: wave w owns rows 8w..8w+7, lane == d
    const int wave = t >> 6;
    const int lane = t & 63;
    const int rbase = wave * 8;
    float acc[8];
    #pragma unroll
    for (int j = 0; j < 8; ++j) acc[j] = 0.f;
    #pragma unroll
    for (int j = 0; j < 8; ++j) {
        const unsigned int ks = rowstart[rbase + j];
        const unsigned int ke = rowstart[rbase + j + 1];
        for (unsigned int k = ks; k < ke; ++k) {
            const int2 en = sorted[k];              // uniform across the wave
            acc[j] = fmaf(__int_as_float(en.y),
                          X[((size_t)(en.x & 0xFFFF) << 6) + lane], acc[j]);
        }
    }
    float* obase = out + ((size_t)bkt * ROWS_PER_BKT + rbase) * ND + lane;
    #pragma unroll
    for (int j = 0; j < 8; ++j) obase[(size_t)j * ND] = acc[j];
}

// ---------------------------------------------------------------------------
// Pass 3: spill entries (expected 0). Runs after accum's overwrite; adds.
// ---------------------------------------------------------------------------
__global__ void spill_kernel(const unsigned int* __restrict__ spill_cnt,
                             const int2* __restrict__ spill,
                             const float* __restrict__ X,
                             float* __restrict__ out) {
    const unsigned int n = min(*spill_cnt, (unsigned int)SPILLCAP);
    const int lane = threadIdx.x & 63;
    const int g0   = blockIdx.x * (blockDim.x >> 6) + (threadIdx.x >> 6);
    const int gstr = gridDim.x * (blockDim.x >> 6);
    for (unsigned int k = g0; k < n; k += gstr) {
        const int2 e   = spill[k];
        const int xrow = e.x & 0xFFFF;
        const int seg  = (e.x >> 16) & 0xFFFF;
        atomicAdd(&out[((size_t)seg << 6) + lane],
                  __int_as_float(e.y) * X[((size_t)xrow << 6) + lane]);
    }
}

// ---------------------------------------------------------------------------
// Fallback: round-2 proven atomic scatter (unexpected shape or small ws).
// ---------------------------------------------------------------------------
__global__ void coo_scatter_kernel(const int* __restrict__ Ab,
                                   const int* __restrict__ Ar,
                                   const int* __restrict__ Ac,
                                   const float* __restrict__ Av,
                                   const float* __restrict__ X,
                                   const unsigned int* __restrict__ Xm,
                                   const unsigned int* __restrict__ Tm,
                                   float* __restrict__ out, int nnz) {
    const int groups_per_block = blockDim.x >> 6;
    const int g0 = blockIdx.x * groups_per_block + (threadIdx.x >> 6);
    const int gstr = gridDim.x * groups_per_block;
    const int lane = threadIdx.x & 63;
    for (int e = g0; e < nnz; e += gstr) {
        const int b = Ab[e];
        const int r = Ar[e];
        if (!Tm[b * NN + r]) continue;
        const int c = Ac[e];
        if (!Xm[b * NN + c]) continue;
        const float v = Av[e];
        const float x = X[((size_t)(b * NN + c)) * ND + lane];
        atomicAdd(&out[((size_t)(b * NN + r)) * ND + lane], v * x);
    }
}

extern "C" void kernel_launch(void* const* d_in, const int* in_sizes, int n_in,
                              void* d_out, int out_size, void* d_ws, size_t ws_size,
                              hipStream_t stream) {
    const int*   Ab = (const int*)d_in[0];
    const int*   Ar = (const int*)d_in[1];
    const int*   Ac = (const int*)d_in[2];
    const float* Av = (const float*)d_in[3];
    const float* X  = (const float*)d_in[4];
    const void*  Xm_raw = d_in[5];
    const void*  Tm_raw = d_in[6];
    float* out = (float*)d_out;

    const int nnz   = in_sizes[0];
    const int nmask = in_sizes[5];   // B*N

    // Workspace layout (8B aligned)
    unsigned char* w = (unsigned char*)d_ws;
    unsigned int* xm        = (unsigned int*)w;  w += (size_t)nmask * 4;
    unsigned int* tm        = (unsigned int*)w;  w += (size_t)nmask * 4;
    unsigned int* cnt       = (unsigned int*)w;  w += (size_t)NSLOT * CNT_STRIDE * 4;
    unsigned int* spill_cnt = (unsigned int*)w;  w += 16;
    int2*         buckets   = (int2*)w;          w += (size_t)NSLOT * SUBCAP * 8;
    int2*         spill     = (int2*)w;          w += (size_t)SPILLCAP * 8;
    const size_t needed = (size_t)(w - (unsigned char*)d_ws);

    mask_prep_kernel<<<(nmask + 255) / 256, 256, 0, stream>>>(Xm_raw, Tm_raw, xm, tm, nmask);

    // Fast path requires the known problem shape (16-bit xrow/seg packing,
    // sub-bucket capacity sized for nnz=2M at ~25% survival).
    if (ws_size < needed || nmask != NBKT * ROWS_PER_BKT || (nnz & 3) || nnz > (1 << 22)) {
        hipMemsetAsync(d_out, 0, (size_t)out_size * sizeof(float), stream);
        coo_scatter_kernel<<<16384, 256, 0, stream>>>(Ab, Ar, Ac, Av, X, xm, tm, out, nnz);
        return;
    }

    // Zero padded counters + spill counter in one memset. No out memset:
    // accum_kernel writes every output row.
    hipMemsetAsync(cnt, 0, (size_t)NSLOT * CNT_STRIDE * 4 + 16, stream);

    const int nq = nnz >> 2;                 // 524288 int4 groups
    bin_kernel<<<2048, 256, 0, stream>>>(Ab, Ar, Ac, Av, xm, tm,
                                         cnt, buckets, spill_cnt, spill, nq);
    accum_kernel<<<NBKT, 1024, 0, stream>>>(cnt, buckets, X, out);
    spill_kernel<<<16, 256, 0, stream>>>(spill_cnt, spill, X, out);
}

// Round 11
// 152.208 us; speedup vs baseline: 2.4782x; 1.1488x over previous
//
#include <hip/hip_runtime.h>

// Problem constants (reference: B=8, N=8192, D=64, NNZ=2097152)
#define NB 8
#define NN 8192
#define ND 64

// Binning geometry: 512 buckets x 128 output rows; 4 sub-buckets each.
// Counters padded to one per 64B line (round-6 lesson: packed counters =
// 4K serialized atomics/line = 160us). SUBCAP=512 vs mean 256 (~16 sigma).
#define NBKT 512
#define ROWS_PER_BKT 128
#define SUB 4
#define NSLOT (NBKT * SUB)      // 2048
#define SUBCAP 512
#define BKT_CAP (SUB * SUBCAP)  // 2048 entries max per bucket
#define CNT_STRIDE 16           // 64B per counter
#define SPILLCAP 16384

// Mask format detection, in-kernel (bool upload convention unknown:
// 1-byte vs int32). Wave-parallel: any of the first 256 words of X_mask
// > 1 => byte-packed bools. All blocks read the same 1KB (L2 broadcast).
__device__ __forceinline__ bool detect_bytes_block(const void* xm_raw,
                                                   int* s_flag) {
    if (threadIdx.x == 0) *s_flag = 0;
    __syncthreads();
    const unsigned int* w = (const unsigned int*)xm_raw;
    if (threadIdx.x < 256 && w[threadIdx.x] > 1u) atomicOr(s_flag, 1);
    __syncthreads();
    return *s_flag != 0;
}

__device__ __forceinline__ unsigned int mask_at(const void* m, bool bytes, int i) {
    return bytes ? (unsigned int)((const unsigned char*)m)[i]
                 : ((const unsigned int*)m)[i];
}

// ---------------------------------------------------------------------------
// Pass 1: bin surviving edges into sub-buckets. int4-vectorized index reads,
// raw-mask lookups (L2-hot). Entry = (xrow | row_in_bucket<<16, val_bits).
// ---------------------------------------------------------------------------
__global__ void bin_kernel(const int* __restrict__ Ab, const int* __restrict__ Ar,
                           const int* __restrict__ Ac, const float* __restrict__ Av,
                           const void* __restrict__ Xm_raw,
                           const void* __restrict__ Tm_raw,
                           unsigned int* __restrict__ cnt,
                           int2* __restrict__ buckets,
                           unsigned int* __restrict__ spill_cnt,
                           int2* __restrict__ spill,
                           int nq) {
    __shared__ int s_flag;
    const bool bytes = detect_bytes_block(Xm_raw, &s_flag);

    const int sub = blockIdx.x & (SUB - 1);
    const int4*   Ab4 = (const int4*)Ab;
    const int4*   Ar4 = (const int4*)Ar;
    const int4*   Ac4 = (const int4*)Ac;
    const float4* Av4 = (const float4*)Av;
    int i = blockIdx.x * blockDim.x + threadIdx.x;
    const int str = gridDim.x * blockDim.x;
    for (; i < nq; i += str) {
        const int4   b4 = Ab4[i];
        const int4   r4 = Ar4[i];
        const int4   c4 = Ac4[i];
        const float4 v4 = Av4[i];
        const int   bs[4] = {b4.x, b4.y, b4.z, b4.w};
        const int   rs[4] = {r4.x, r4.y, r4.z, r4.w};
        const int   cs[4] = {c4.x, c4.y, c4.z, c4.w};
        const float vs[4] = {v4.x, v4.y, v4.z, v4.w};
        #pragma unroll
        for (int j = 0; j < 4; ++j) {
            const int seg  = bs[j] * NN + rs[j];
            const int xrow = bs[j] * NN + cs[j];
            if (mask_at(Tm_raw, bytes, seg) && mask_at(Xm_raw, bytes, xrow)) {
                const int slot = (seg >> 7) * SUB + sub;
                const unsigned int pos = atomicAdd(&cnt[slot * CNT_STRIDE], 1u);
                if (pos < SUBCAP) {
                    buckets[(size_t)slot * SUBCAP + pos] =
                        make_int2(xrow | ((seg & (ROWS_PER_BKT - 1)) << 16),
                                  __float_as_int(vs[j]));
                } else {
                    const unsigned int sp = atomicAdd(spill_cnt, 1u);
                    if (sp < SPILLCAP)
                        spill[sp] = make_int2(xrow | (seg << 16), __float_as_int(vs[j]));
                }
            }
        }
    }
}

// ---------------------------------------------------------------------------
// Pass 2: one block (1024 thr) per bucket.
//   a) stage <=2048 entries  b) LDS u32 histogram by row  c) wave-0 shfl scan
//   d) counting-sort into LDS  e) wave w accumulates rows 8w..8w+7 in VGPRs,
//      unroll-4 for 4 outstanding X gathers (round-10: serial chain = 50us),
//      folds any spill entries (expected 0), writes 8 coalesced 256B rows.
//   Writes every output row -> no global memset of out needed.
// ---------------------------------------------------------------------------
__global__ __launch_bounds__(1024) void accum_kernel(const unsigned int* __restrict__ cnt,
                                                     const int2* __restrict__ buckets,
                                                     const float* __restrict__ X,
                                                     const unsigned int* __restrict__ spill_cnt,
                                                     const int2* __restrict__ spill,
                                                     float* __restrict__ out) {
    __shared__ int2 sorted[BKT_CAP];                   // 16 KB
    __shared__ unsigned int hist[ROWS_PER_BKT];
    __shared__ unsigned int rowstart[ROWS_PER_BKT + 1];
    __shared__ unsigned int cursor[ROWS_PER_BKT];
    __shared__ unsigned int s_n[SUB];
    __shared__ unsigned int s_nsp;

    const int bkt = blockIdx.x;
    const int t = threadIdx.x;

    if (t < ROWS_PER_BKT) hist[t] = 0;
    if (t < SUB) s_n[t] = min(cnt[(bkt * SUB + t) * CNT_STRIDE], (unsigned int)SUBCAP);
    if (t == 0) s_nsp = min(*spill_cnt, (unsigned int)SPILLCAP);
    __syncthreads();

    // a+b) stage + histogram
    int2 e0s, e1s;
    int r0 = -1, r1 = -1;
    {
        int idx = t, sub = idx >> 9, off = idx & (SUBCAP - 1);
        if ((unsigned int)off < s_n[sub]) {
            e0s = buckets[(size_t)(bkt * SUB + sub) * SUBCAP + off];
            r0 = (e0s.x >> 16) & (ROWS_PER_BKT - 1);
            atomicAdd(&hist[r0], 1u);
        }
        idx = t + 1024; sub = idx >> 9; off = idx & (SUBCAP - 1);
        if ((unsigned int)off < s_n[sub]) {
            e1s = buckets[(size_t)(bkt * SUB + sub) * SUBCAP + off];
            r1 = (e1s.x >> 16) & (ROWS_PER_BKT - 1);
            atomicAdd(&hist[r1], 1u);
        }
    }
    __syncthreads();

    // c) exclusive scan of 128 counts by wave 0
    if (t < 64) {
        const unsigned int h0 = hist[t], h1 = hist[64 + t];
        unsigned int a = h0, b = h1;
        for (int off = 1; off < 64; off <<= 1) {
            unsigned int v = __shfl_up(a, off);
            if (t >= off) a += v;
        }
        const unsigned int atot = __shfl(a, 63);
        for (int off = 1; off < 64; off <<= 1) {
            unsigned int v = __shfl_up(b, off);
            if (t >= off) b += v;
        }
        rowstart[t]      = a - h0;
        rowstart[64 + t] = atot + b - h1;
        cursor[t]        = a - h0;
        cursor[64 + t]   = atot + b - h1;
        if (t == 63) rowstart[128] = atot + b;
    }
    __syncthreads();

    // d) counting-sort into LDS
    if (r0 >= 0) { const unsigned int p = atomicAdd(&cursor[r0], 1u); sorted[p] = e0s; }
    if (r1 >= 0) { const unsigned int p = atomicAdd(&cursor[r1], 1u); sorted[p] = e1s; }
    __syncthreads();

    // e) register accumulation, unroll-4 (4 outstanding gathers)
    const int wave = t >> 6;
    const int lane = t & 63;
    const int rbase = wave * 8;
    float acc[8];
    #pragma unroll
    for (int j = 0; j < 8; ++j) {
        unsigned int k = rowstart[rbase + j];
        const unsigned int ke = rowstart[rbase + j + 1];
        float a = 0.f;
        for (; k + 4 <= ke; k += 4) {
            const int2 e0 = sorted[k],     e1 = sorted[k + 1];
            const int2 e2 = sorted[k + 2], e3 = sorted[k + 3];
            const float x0 = X[((size_t)(e0.x & 0xFFFF) << 6) + lane];
            const float x1 = X[((size_t)(e1.x & 0xFFFF) << 6) + lane];
            const float x2 = X[((size_t)(e2.x & 0xFFFF) << 6) + lane];
            const float x3 = X[((size_t)(e3.x & 0xFFFF) << 6) + lane];
            a = fmaf(__int_as_float(e0.y), x0, a);
            a = fmaf(__int_as_float(e1.y), x1, a);
            a = fmaf(__int_as_float(e2.y), x2, a);
            a = fmaf(__int_as_float(e3.y), x3, a);
        }
        for (; k < ke; ++k) {
            const int2 e = sorted[k];
            a = fmaf(__int_as_float(e.y), X[((size_t)(e.x & 0xFFFF) << 6) + lane], a);
        }
        acc[j] = a;
    }

    // fold spill entries (expected none); static acc indexing (rule #20)
    if (s_nsp) {
        const int seglo = bkt * ROWS_PER_BKT;
        for (unsigned int k = 0; k < s_nsp; ++k) {
            const int2 e = spill[k];
            const int r = ((e.x >> 16) & 0xFFFF) - seglo;
            if (r >= rbase && r < rbase + 8) {
                const float xv = X[((size_t)(e.x & 0xFFFF) << 6) + lane];
                const float vv = __int_as_float(e.y);
                #pragma unroll
                for (int j = 0; j < 8; ++j)
                    if (r == rbase + j) acc[j] = fmaf(vv, xv, acc[j]);
            }
        }
    }

    float* obase = out + ((size_t)bkt * ROWS_PER_BKT + rbase) * ND + lane;
    #pragma unroll
    for (int j = 0; j < 8; ++j) obase[(size_t)j * ND] = acc[j];
}

// ---------------------------------------------------------------------------
// Fallback: proven atomic scatter (unexpected shape or small ws), raw masks.
// ---------------------------------------------------------------------------
__global__ void coo_scatter_kernel(const int* __restrict__ Ab,
                                   const int* __restrict__ Ar,
                                   const int* __restrict__ Ac,
                                   const float* __restrict__ Av,
                                   const float* __restrict__ X,
                                   const void* __restrict__ Xm_raw,
                                   const void* __restrict__ Tm_raw,
                                   float* __restrict__ out, int nnz) {
    __shared__ int s_flag;
    const bool bytes = detect_bytes_block(Xm_raw, &s_flag);
    const int groups_per_block = blockDim.x >> 6;
    const int g0 = blockIdx.x * groups_per_block + (threadIdx.x >> 6);
    const int gstr = gridDim.x * groups_per_block;
    const int lane = threadIdx.x & 63;
    for (int e = g0; e < nnz; e += gstr) {
        const int b = Ab[e];
        const int r = Ar[e];
        if (!mask_at(Tm_raw, bytes, b * NN + r)) continue;
        const int c = Ac[e];
        if (!mask_at(Xm_raw, bytes, b * NN + c)) continue;
        const float v = Av[e];
        const float x = X[((size_t)(b * NN + c)) * ND + lane];
        atomicAdd(&out[((size_t)(b * NN + r)) * ND + lane], v * x);
    }
}

extern "C" void kernel_launch(void* const* d_in, const int* in_sizes, int n_in,
                              void* d_out, int out_size, void* d_ws, size_t ws_size,
                              hipStream_t stream) {
    const int*   Ab = (const int*)d_in[0];
    const int*   Ar = (const int*)d_in[1];
    const int*   Ac = (const int*)d_in[2];
    const float* Av = (const float*)d_in[3];
    const float* X  = (const float*)d_in[4];
    const void*  Xm_raw = d_in[5];
    const void*  Tm_raw = d_in[6];
    float* out = (float*)d_out;

    const int nnz   = in_sizes[0];
    const int nmask = in_sizes[5];   // B*N

    // Workspace layout (8B aligned)
    unsigned char* w = (unsigned char*)d_ws;
    unsigned int* cnt       = (unsigned int*)w;  w += (size_t)NSLOT * CNT_STRIDE * 4;
    unsigned int* spill_cnt = (unsigned int*)w;  w += 16;
    int2*         buckets   = (int2*)w;          w += (size_t)NSLOT * SUBCAP * 8;
    int2*         spill     = (int2*)w;          w += (size_t)SPILLCAP * 8;
    const size_t needed = (size_t)(w - (unsigned char*)d_ws);

    // Fast path requires the known problem shape (16-bit xrow/seg packing,
    // sub-bucket capacity sized for nnz=2M at ~25% survival).
    if (ws_size < needed || nmask != NBKT * ROWS_PER_BKT || (nnz & 3) || nnz > (1 << 22)) {
        hipMemsetAsync(d_out, 0, (size_t)out_size * sizeof(float), stream);
        coo_scatter_kernel<<<16384, 256, 0, stream>>>(Ab, Ar, Ac, Av, X,
                                                      Xm_raw, Tm_raw, out, nnz);
        return;
    }

    // Zero padded counters + spill counter in one memset (ws re-poisoned 0xAA
    // before every timed launch). No out memset: accum writes every row.
    hipMemsetAsync(cnt, 0, (size_t)NSLOT * CNT_STRIDE * 4 + 16, stream);

    const int nq = nnz >> 2;                 // 524288 int4 groups
    bin_kernel<<<2048, 256, 0, stream>>>(Ab, Ar, Ac, Av, Xm_raw, Tm_raw,
                                         cnt, buckets, spill_cnt, spill, nq);
    accum_kernel<<<NBKT, 1024, 0, stream>>>(cnt, buckets, X, spill_cnt, spill, out);
}